// Round 7
// baseline (73.533 us; speedup 1.0000x reference)
//
#include <hip/hip_runtime.h>
#include <math.h>

#define BB 8
#define NN 2048
#define IN_DIM 256
#define OUT_DIM 128
#define M_TOT (BB*NN)          // 16384
#define CHUNK 32
#define NCHUNK (NN/CHUNK)      // 64
#define LDP 264                // padded rank-chunk stride (floats)
#define NBUCKET (BB*NCHUNK)    // 512

// ---------------- workspace layout (in floats) ----------------
static const size_t OFF_H    = 0;                                   // h: M_TOT*128
static const size_t OFF_SRC  = OFF_H   + (size_t)M_TOT*OUT_DIM;
static const size_t OFF_DST  = OFF_SRC + M_TOT;
static const size_t OFF_SD   = OFF_DST + M_TOT;                     // sorted_d
static const size_t OFF_SI   = OFF_SD  + M_TOT;                     // sorted_idx (int)
static const size_t OFF_WP   = OFF_SI  + M_TOT;                     // wpos (sorted order)
static const size_t OFF_WN   = OFF_WP  + M_TOT;                     // wneg
static const size_t OFF_CP   = OFF_WN  + M_TOT;                     // chunk sums
static const size_t OFF_CN   = OFF_CP  + (size_t)NBUCKET*OUT_DIM;
static const size_t OFF_CPW  = OFF_CN  + (size_t)NBUCKET*OUT_DIM;
static const size_t OFF_CNW  = OFF_CPW + NBUCKET;
static const size_t OFF_LO   = OFF_CNW + NBUCKET;                   // lo per query (int)
static const size_t OFF_BCNT = OFF_LO  + M_TOT;                     // bucket counts (int)
static const size_t OFF_BLST = OFF_BCNT + NBUCKET;                  // bucket lists (int)
// total ~3.4M floats = ~13.6 MB

// ---------------- Kernel A: h = x @ W^T, plus src/dst dots ----------------
__global__ __launch_bounds__(256, 2) void gat_gemm_kernel(
    const float* __restrict__ x, const float* __restrict__ W,
    const float* __restrict__ a_src, const float* __restrict__ a_dst,
    float* __restrict__ h, float* __restrict__ src, float* __restrict__ dstv)
{
    __shared__ float xs[32][34];
    __shared__ float wsh[32][132];
    __shared__ float redS[32][16];
    __shared__ float redD[32][16];
    const int tid = threadIdx.x;
    const int m0 = blockIdx.x * 32;
    const int mt = tid >> 4;
    const int ot = tid & 15;
    float acc[2][8];
#pragma unroll
    for (int i = 0; i < 2; ++i)
#pragma unroll
        for (int j = 0; j < 8; ++j) acc[i][j] = 0.f;

    const float4* x4 = (const float4*)x;
    const float4* W4 = (const float4*)W;

    for (int k0 = 0; k0 < IN_DIM; k0 += 32) {
        {
            int row = tid >> 3, c4 = tid & 7;
            float4 v = x4[(size_t)(m0 + row) * (IN_DIM / 4) + (k0 >> 2) + c4];
            xs[c4 * 4 + 0][row] = v.x; xs[c4 * 4 + 1][row] = v.y;
            xs[c4 * 4 + 2][row] = v.z; xs[c4 * 4 + 3][row] = v.w;
        }
#pragma unroll
        for (int it = 0; it < 4; ++it) {
            int idx = tid + it * 256;
            int o = idx >> 3, c4 = idx & 7;
            float4 v = W4[(size_t)o * (IN_DIM / 4) + (k0 >> 2) + c4];
            wsh[c4 * 4 + 0][o] = v.x; wsh[c4 * 4 + 1][o] = v.y;
            wsh[c4 * 4 + 2][o] = v.z; wsh[c4 * 4 + 3][o] = v.w;
        }
        __syncthreads();
#pragma unroll
        for (int k = 0; k < 32; ++k) {
            float2 xv = *(const float2*)&xs[k][mt * 2];
            float4 wa = *(const float4*)&wsh[k][ot * 4];
            float4 wb = *(const float4*)&wsh[k][64 + ot * 4];
            float xm[2] = {xv.x, xv.y};
            float wv[8] = {wa.x, wa.y, wa.z, wa.w, wb.x, wb.y, wb.z, wb.w};
#pragma unroll
            for (int i = 0; i < 2; ++i)
#pragma unroll
                for (int j = 0; j < 8; ++j)
                    acc[i][j] = fmaf(xm[i], wv[j], acc[i][j]);
        }
        __syncthreads();
    }

    float as8[8], ad8[8];
#pragma unroll
    for (int j = 0; j < 4; ++j) {
        as8[j]     = a_src[ot * 4 + j];      ad8[j]     = a_dst[ot * 4 + j];
        as8[4 + j] = a_src[64 + ot * 4 + j]; ad8[4 + j] = a_dst[64 + ot * 4 + j];
    }
#pragma unroll
    for (int i = 0; i < 2; ++i) {
        int m = m0 + mt * 2 + i;
        float4 v0 = {acc[i][0], acc[i][1], acc[i][2], acc[i][3]};
        float4 v1 = {acc[i][4], acc[i][5], acc[i][6], acc[i][7]};
        ((float4*)h)[(size_t)m * (OUT_DIM / 4) + ot] = v0;
        ((float4*)h)[(size_t)m * (OUT_DIM / 4) + 16 + ot] = v1;
        float ps = 0.f, pd = 0.f;
#pragma unroll
        for (int j = 0; j < 8; ++j) {
            ps = fmaf(acc[i][j], as8[j], ps);
            pd = fmaf(acc[i][j], ad8[j], pd);
        }
        redS[mt * 2 + i][ot] = ps;
        redD[mt * 2 + i][ot] = pd;
    }
    __syncthreads();
    if (tid < 32) {
        float ss = 0.f, dd = 0.f;
#pragma unroll
        for (int t = 0; t < 16; ++t) { ss += redS[tid][t]; dd += redD[tid][t]; }
        src[m0 + tid] = ss;
        dstv[m0 + tid] = dd;
    }
}

// ---------------- Kernel R: fused rank + scatter + weights (+bucket zero) ----------------
__global__ __launch_bounds__(256) void rank_kernel(
    const float* __restrict__ dstv, const int* __restrict__ mask,
    float* __restrict__ sorted_d, int* __restrict__ sorted_idx,
    float* __restrict__ wpos, float* __restrict__ wneg,
    int* __restrict__ bucketCnt)
{
    __shared__ float ld[8 * LDP];
    __shared__ int   red[32][8];
    const int tid = threadIdx.x;
    const int b  = blockIdx.x >> 6;
    const int jg = blockIdx.x & 63;
    if (tid == 0) bucketCnt[blockIdx.x] = 0;   // 512 blocks <-> 512 buckets
    for (int i = tid; i < NN; i += 256)
        ld[(i >> 8) * LDP + (i & 255)] = dstv[b * NN + i];
    __syncthreads();
    const int js = tid >> 3;
    const int qq = tid & 7;
    const int jloc = jg * 32 + js;
    float myd = ld[(jloc >> 8) * LDP + (jloc & 255)];
    const float4* l4 = (const float4*)&ld[qq * LDP];
    int rank = 0;
#pragma unroll 8
    for (int t = 0; t < 64; ++t) {
        float4 v = l4[t];
        int jj = qq * 256 + t * 4;
        rank += (v.x < myd) || (v.x == myd && jj + 0 < jloc);
        rank += (v.y < myd) || (v.y == myd && jj + 1 < jloc);
        rank += (v.z < myd) || (v.z == myd && jj + 2 < jloc);
        rank += (v.w < myd) || (v.w == myd && jj + 3 < jloc);
    }
    red[js][qq] = rank;
    __syncthreads();
    if (tid < 32) {
        int j = jg * 32 + tid;
        const int* rr = red[tid];
        int rk = rr[0] + rr[1] + rr[2] + rr[3] + rr[4] + rr[5] + rr[6] + rr[7];
        float d = ld[(j >> 8) * LDP + (j & 255)];
        int mk = mask[b * NN + j];
        sorted_d[b * NN + rk] = d;
        sorted_idx[b * NN + rk] = j;
        wpos[b * NN + rk] = mk ? expf(d) : 0.f;
        wneg[b * NN + rk] = mk ? expf(0.2f * d) : 0.f;
    }
}

// ---------------- Kernel D1: chunk sums + query search/bucketing ----------------
__global__ __launch_bounds__(256) void chunksum_kernel(
    const float* __restrict__ h, const int* __restrict__ sidx,
    const float* __restrict__ wpos, const float* __restrict__ wneg,
    const float* __restrict__ sorted_d, const float* __restrict__ src,
    float* __restrict__ cPos, float* __restrict__ cNeg,
    float* __restrict__ cPosW, float* __restrict__ cNegW,
    int* __restrict__ lo_arr, int* __restrict__ bucketCnt, int* __restrict__ bucketList)
{
    __shared__ float sd_s[NN];     // 8 KB
    const int tid = threadIdx.x;
    const int b = blockIdx.x >> 6;
    const int c = blockIdx.x & 63;
    const int r0 = c * CHUNK;
    // stage sorted_d for batch (256 thr x 2 float4)
    const float4* sd4 = (const float4*)(sorted_d + b * NN);
    {
        float4 v0 = sd4[tid];
        *(float4*)&sd_s[tid * 4] = v0;
        float4 v1 = sd4[256 + tid];
        *(float4*)&sd_s[1024 + tid * 4] = v1;
    }
    __syncthreads();
    if (tid < 128) {
        int o = tid;
        float ap = 0.f, an = 0.f, apw = 0.f, anw = 0.f;
        for (int r = 0; r < CHUNK; ++r) {
            int rr = b * NN + r0 + r;
            int jj = sidx[rr];
            float wp = wpos[rr], wn = wneg[rr];
            float hv = h[((size_t)b * NN + jj) * OUT_DIM + o];
            ap = fmaf(wp, hv, ap);
            an = fmaf(wn, hv, an);
            apw += wp; anw += wn;
        }
        int cidx = blockIdx.x;
        cPos[(size_t)cidx * OUT_DIM + o] = ap;
        cNeg[(size_t)cidx * OUT_DIM + o] = an;
        if (o == 0) { cPosW[cidx] = apw; cNegW[cidx] = anw; }
    } else if (tid < 160) {
        // binary search for this block's 32 queries, bucket by split-chunk
        int ql = r0 + (tid - 128);
        int q = b * NN + ql;
        float t = -src[q];
        int lo = 0, hi = NN;
        while (lo < hi) {
            int mid = (lo + hi) >> 1;
            if (sd_s[mid] > t) hi = mid; else lo = mid + 1;
        }
        lo_arr[q] = lo;
        int cq = lo >> 5; if (cq > NCHUNK - 1) cq = NCHUNK - 1;
        int bidx = b * NCHUNK + cq;
        int pos = atomicAdd(&bucketCnt[bidx], 1);
        bucketList[(size_t)bidx * NN + pos] = q;
    }
}

// ---------------- Kernel E: fused expand + query (per split-chunk bucket) ----------------
__global__ __launch_bounds__(256, 2) void fusedout_kernel(
    const float* __restrict__ h, const int* __restrict__ sidx,
    const float* __restrict__ wpos, const float* __restrict__ wneg,
    const float* __restrict__ cPos, const float* __restrict__ cNeg,
    const float* __restrict__ cPosW, const float* __restrict__ cNegW,
    const float* __restrict__ src, const int* __restrict__ lo_arr,
    const int* __restrict__ bucketCnt, const int* __restrict__ bucketList,
    float* __restrict__ out)
{
    __shared__ float hs[CHUNK][OUT_DIM];          // 16 KB
    __shared__ float PreL[CHUNK + 1][OUT_DIM];    // 16.9 KB (includes cross-chunk base)
    __shared__ float SufL[CHUNK + 1][OUT_DIM];    // 16.9 KB
    __shared__ float wn_s[CHUNK], wp_s[CHUNK];
    __shared__ int   si_s[CHUNK];
    __shared__ float prewL[CHUNK + 1], sufwL[CHUNK + 1];
    const int tid = threadIdx.x;
    const int b = blockIdx.x >> 6;
    const int c = blockIdx.x & 63;
    const int r0 = c * CHUNK;
    const size_t hb = (size_t)b * NN;

    if (tid < CHUNK) {
        int rr = b * NN + r0 + tid;
        si_s[tid] = sidx[rr];
        wn_s[tid] = wneg[rr];
        wp_s[tid] = wpos[rr];
    }
    __syncthreads();
    // stage 32 gathered h rows (32 rows x 32 float4 = 1024 / 256 thr = 4 each)
#pragma unroll
    for (int it = 0; it < 4; ++it) {
        int row = it * 8 + (tid >> 5);
        int c4 = tid & 31;
        float4 v = ((const float4*)h)[(hb + si_s[row]) * (OUT_DIM / 4) + c4];
        *(float4*)&hs[row][c4 * 4] = v;
    }
    // cross-chunk bases (independent global loads, overlap with staging)
    float base = 0.f;
    if (tid < 128) {
        for (int cc = 0; cc < c; ++cc)
            base += cNeg[(size_t)(b * NCHUNK + cc) * OUT_DIM + tid];
    } else {
        int o = tid - 128;
        for (int cc = c + 1; cc < NCHUNK; ++cc)
            base += cPos[(size_t)(b * NCHUNK + cc) * OUT_DIM + o];
    }
    __syncthreads();
    // local prefix (incl. base) and suffix (incl. base), same accumulation order as before
    if (tid < 128) {
        int o = tid;
        float acc = base;
#pragma unroll
        for (int r = 0; r < CHUNK; ++r) {
            PreL[r][o] = acc;
            acc = fmaf(wn_s[r], hs[r][o], acc);
        }
        PreL[CHUNK][o] = acc;
    } else {
        int o = tid - 128;
        float acc = base;
        SufL[CHUNK][o] = acc;
#pragma unroll
        for (int r = CHUNK - 1; r >= 0; --r) {
            acc = fmaf(wp_s[r], hs[r][o], acc);
            SufL[r][o] = acc;
        }
    }
    if (tid == 0) {
        float a = 0.f;
        for (int cc = 0; cc < c; ++cc) a += cNegW[b * NCHUNK + cc];
        for (int r = 0; r < CHUNK; ++r) { prewL[r] = a; a += wn_s[r]; }
        prewL[CHUNK] = a;
    }
    if (tid == 128) {
        float a = 0.f;
        for (int cc = c + 1; cc < NCHUNK; ++cc) a += cPosW[b * NCHUNK + cc];
        sufwL[CHUNK] = a;
        for (int r = CHUNK - 1; r >= 0; --r) { a += wp_s[r]; sufwL[r] = a; }
    }
    __syncthreads();

    // answer this bucket's queries (2 per iteration: 2 x 128 threads)
    const int bidx = blockIdx.x;
    const int cnt = bucketCnt[bidx];
    const int o  = tid & 127;
    const int qh = tid >> 7;
    for (int i = qh; i < cnt; i += 2) {
        int q = bucketList[(size_t)bidx * NN + i];
        int rl = lo_arr[q] - r0;               // 0..32
        float sv = src[q];
        float pe = expf(sv), pn = expf(0.2f * sv);
        float den = pe * sufwL[rl] + pn * prewL[rl];
        float sc = (den > 0.f) ? 1.f / den : 0.f;
        float num = pe * SufL[rl][o] + pn * PreL[rl][o];
        out[(size_t)q * OUT_DIM + o] = num * sc;
    }
}

// ---------------- launcher ----------------
extern "C" void kernel_launch(void* const* d_in, const int* in_sizes, int n_in,
                              void* d_out, int out_size, void* d_ws, size_t ws_size,
                              hipStream_t stream)
{
    const float* x     = (const float*)d_in[0];
    const int*   mask  = (const int*)d_in[1];
    const float* W     = (const float*)d_in[2];
    const float* a_src = (const float*)d_in[3];
    const float* a_dst = (const float*)d_in[4];
    float* out = (float*)d_out;
    float* ws  = (float*)d_ws;

    float* h        = ws + OFF_H;
    float* src      = ws + OFF_SRC;
    float* dstv     = ws + OFF_DST;
    float* sorted_d = ws + OFF_SD;
    int*   sidx     = (int*)(ws + OFF_SI);
    float* wpos     = ws + OFF_WP;
    float* wneg     = ws + OFF_WN;
    float* cPos     = ws + OFF_CP;
    float* cNeg     = ws + OFF_CN;
    float* cPosW    = ws + OFF_CPW;
    float* cNegW    = ws + OFF_CNW;
    int*   lo_arr   = (int*)(ws + OFF_LO);
    int*   bucketCnt= (int*)(ws + OFF_BCNT);
    int*   bucketList=(int*)(ws + OFF_BLST);

    gat_gemm_kernel<<<M_TOT / 32, 256, 0, stream>>>(x, W, a_src, a_dst, h, src, dstv);
    rank_kernel<<<NBUCKET, 256, 0, stream>>>(dstv, mask, sorted_d, sidx, wpos, wneg, bucketCnt);
    chunksum_kernel<<<NBUCKET, 256, 0, stream>>>(h, sidx, wpos, wneg, sorted_d, src,
                                                 cPos, cNeg, cPosW, cNegW,
                                                 lo_arr, bucketCnt, bucketList);
    fusedout_kernel<<<NBUCKET, 256, 0, stream>>>(h, sidx, wpos, wneg, cPos, cNeg, cPosW, cNegW,
                                                 src, lo_arr, bucketCnt, bucketList, out);
}